// Round 10
// baseline (192.252 us; speedup 1.0000x reference)
//
#include <hip/hip_runtime.h>

#define NN 40000
#define NE 640000
#define BN_EPS 1e-5f

typedef __attribute__((ext_vector_type(8))) short bf16x8;
typedef __attribute__((ext_vector_type(4))) float f32x4;
typedef unsigned int uint;
typedef unsigned short ushort;

__device__ __forceinline__ float blo(uint u) { return __uint_as_float(u << 16); }
__device__ __forceinline__ float bhi(uint u) { return __uint_as_float(u & 0xFFFF0000u); }
__device__ __forceinline__ uint bpack(float lo, float hi) {
    uint a = __float_as_uint(lo); a = (a + 0x7FFFu + ((a >> 16) & 1u)) >> 16;        // RNE
    uint b = __float_as_uint(hi); b = (b + 0x7FFFu + ((b >> 16) & 1u)) & 0xFFFF0000u;
    return a | b;
}
__device__ __forceinline__ ushort b1pack(float v) {
    uint u = __float_as_uint(v); return (ushort)((u + 0x7FFFu + ((u >> 16) & 1u)) >> 16);
}
__device__ __forceinline__ uint4 cvt8(const float4* f4, int i) {
    float4 p = f4[i * 2], q = f4[i * 2 + 1];
    uint4 o;
    o.x = bpack(p.x, p.y); o.y = bpack(p.z, p.w);
    o.z = bpack(q.x, q.y); o.w = bpack(q.z, q.w);
    return o;
}

// ---------------- K1: dst-partitioned bucket || convert x->xs(slice-major), W1, W2 || zero bn ----------------
// Bucket: 4 dst-partitions (10000 nodes, 1.28MB srcl sub-region each). Partition p = b&3 is
// pinned to XCDs {p, p+4} by round-robin dispatch -> its srcl/cnt region stays L2-resident,
// so the 2B scatter RMWs merge in-cache instead of thrashing the L2-miss path (R9 lesson).
// Edges are nt-loaded (streamed 4x, don't pollute the resident region).
__global__ __launch_bounds__(256) void k_prep(const float* __restrict__ x, const float* __restrict__ W1,
                                              const float* __restrict__ W2, const int* __restrict__ ei,
                                              int* __restrict__ cnt, float* __restrict__ bn,
                                              uint* __restrict__ xs, uint* __restrict__ w1b,
                                              uint* __restrict__ w2b, ushort* __restrict__ srcl) {
    int b = blockIdx.x, t = threadIdx.x;
    if (b < 10000) {                                  // bucket: each partition scans all edges
        int p = b & 3;
        int e = (b >> 2) * 256 + t;                   // 2500 chunks * 256 = 640000
        int s = __builtin_nontemporal_load(ei + e);
        int d = __builtin_nontemporal_load(ei + NE + e);
        if ((unsigned)(d - p * 10000) < 10000u) {     // own dst-range only
            int pos = atomicAdd(&cnt[d], 1);
            if (pos < 64) srcl[(size_t)d * 64 + pos] = (ushort)s;
        }
    } else if (b < 12500) {                           // x -> xs slice-major bf16
        int i = (b - 10000) * 256 + t;                // 640000 groups of 8 ch
        uint4 o = cvt8((const float4*)x, i);
        int node = i >> 4, g8 = i & 15;
        int slice = g8 >> 1, half = g8 & 1;           // 8 slices of 16 ch
        *(uint4*)&xs[(size_t)slice * 320000 + node * 8 + half * 4] = o;
    } else if (b < 12508) {                           // W1 -> bf16 (2048 groups)
        int i = (b - 12500) * 256 + t;
        ((uint4*)w1b)[i] = cvt8((const float4*)W1, i);
    } else if (b < 12516) {                           // W2 -> bf16
        int i = (b - 12508) * 256 + t;
        ((uint4*)w2b)[i] = cvt8((const float4*)W2, i);
    } else {                                          // zero bnsum/bnsumsq
        bn[t] = 0.f;
    }
}

// ---------------- K2: XCD-resident sliced gather ----------------
// Slice-major xs: slice g&7 occupies a contiguous 1.28MB region -> fully L2-resident on its
// XCD after first touch (the R9 row-major version shared 128B lines across 4 slices -> 5.1MB
// effective set -> missed; FETCH stayed 136MB). srcl/cnt are nt-loaded so the 8x re-stream
// doesn't evict the x-slice. One load instr covers 8 neighbors x 8 lanes x 4B.
__global__ __launch_bounds__(256) void k_gather(const uint* __restrict__ xs, const int* __restrict__ cnt,
                                                const ushort* __restrict__ srcl, const float* __restrict__ epsp,
                                                uint* __restrict__ hb) {
    const int g = blockIdx.x;
    const int slice = g & 7;                          // XCD-pinned channel slice
    const int ng = g >> 3;                            // node-group 0..1249
    const uint* __restrict__ xsl = xs + (size_t)slice * 320000;
    const int wave = threadIdx.x >> 6;
    const int lane = threadIdx.x & 63;
    const int sub = lane >> 3;                        // neighbor subgroup 0..7
    const int ch = lane & 7;                          // dword within slice (2 ch)
    const float e1 = 1.f + epsp[0];
    const int nbase = ng * 32 + wave * 8;             // 1250*32 = 40000 nodes

#pragma unroll 2
    for (int t = 0; t < 8; ++t) {
        int node = nbase + t;
        int deg = __builtin_nontemporal_load(cnt + node); deg = deg > 64 ? 64 : deg;
        int sv = __builtin_nontemporal_load((const ushort*)srcl + (size_t)node * 64 + lane);
        uint su = xsl[node * 8 + ch];                 // self slice (L2-resident)
        float a0 = 0.f, a1 = 0.f;
        int chunks = (deg + 7) >> 3;
        for (int c = 0; c < chunks; ++c) {
            int n = c * 8 + sub;
            int s = __shfl(sv, n);                    // neighbor id for this subgroup
            bool ok = n < deg;
            s = ok ? s : 0;                           // clamp to row 0 (resident), mask value
            uint v = xsl[s * 8 + ch];                 // L2 hit: own 1.28MB slice
            a0 += ok ? blo(v) : 0.f;
            a1 += ok ? bhi(v) : 0.f;
        }
        a0 += __shfl_xor(a0, 8);  a1 += __shfl_xor(a1, 8);
        a0 += __shfl_xor(a0, 16); a1 += __shfl_xor(a1, 16);
        a0 += __shfl_xor(a0, 32); a1 += __shfl_xor(a1, 32);
        if (sub == 0)                                 // lanes 0-7 write the 32B hb slice (row-major)
            __builtin_nontemporal_store(bpack(fmaf(blo(su), e1, a0), fmaf(bhi(su), e1, a1)),
                                        &hb[(size_t)node * 64 + slice * 8 + ch]);
    }
}

// ---------------- K3: GEMM1 (MFMA bf16): h1b = bf16(hb @ W1b^T + b1), fused BN stats ----------------
// fragments: A[row=l&15][k=(l>>4)*8+j], B[k][col=l&15], C/D col=l&15,row=(l>>4)*4+i
__global__ __launch_bounds__(256) void k_mm1(const ushort* __restrict__ hb, const ushort* __restrict__ w1b,
                                             const float* __restrict__ b1, ushort* __restrict__ h1b,
                                             float* __restrict__ bnsum, float* __restrict__ bnsumsq) {
    __shared__ float rs[256 * 8];
    __shared__ float rq[256 * 8];
    const int tid = threadIdx.x;
    const int wave = tid >> 6;
    const int lane = tid & 63;
    const int lr = lane & 15;
    const int lk = lane >> 4;
    const int r0 = (blockIdx.x * 4 + wave) * 16;     // 625 blocks * 4 waves * 16 rows = 40000

    bf16x8 a[4];
#pragma unroll
    for (int ks = 0; ks < 4; ++ks)
        a[ks] = *reinterpret_cast<const bf16x8*>(&hb[(size_t)(r0 + lr) * 128 + ks * 32 + lk * 8]);

    f32x4 acc[8];
#pragma unroll
    for (int t = 0; t < 8; ++t) { acc[t][0] = 0.f; acc[t][1] = 0.f; acc[t][2] = 0.f; acc[t][3] = 0.f; }

#pragma unroll
    for (int t = 0; t < 8; ++t) {
        const ushort* wrow = &w1b[(size_t)(t * 16 + lr) * 128];
#pragma unroll
        for (int ks = 0; ks < 4; ++ks) {
            bf16x8 bfr = *reinterpret_cast<const bf16x8*>(&wrow[ks * 32 + lk * 8]);
            acc[t] = __builtin_amdgcn_mfma_f32_16x16x32_bf16(a[ks], bfr, acc[t], 0, 0, 0);
        }
    }
#pragma unroll
    for (int t = 0; t < 8; ++t) {
        float bias = b1[t * 16 + lr];
        float s = 0.f, q = 0.f;
#pragma unroll
        for (int i = 0; i < 4; ++i) {
            float v = acc[t][i] + bias;
            h1b[(size_t)(r0 + lk * 4 + i) * 128 + t * 16 + lr] = b1pack(v);
            s += v; q += v * v;
        }
        rs[tid * 8 + t] = s;
        rq[tid * 8 + t] = q;
    }
    __syncthreads();
    if (tid < 128) {
        int c = tid, t = c >> 4, cr = c & 15;
        float s = 0.f, q = 0.f;
#pragma unroll
        for (int w = 0; w < 4; ++w)
#pragma unroll
            for (int g = 0; g < 4; ++g) {
                int src = w * 64 + g * 16 + cr;
                s += rs[src * 8 + t];
                q += rq[src * 8 + t];
            }
        atomicAdd(&bnsum[c], s);
        atomicAdd(&bnsumsq[c], q);
    }
}

// ---------------- K4: GEMM2 (MFMA bf16): out = relu(bn(h1)) @ W2b^T + b2, BN inline ----------------
__global__ __launch_bounds__(256) void k_mm2(const ushort* __restrict__ h1b, const ushort* __restrict__ w2b,
                                             const float* __restrict__ b2,
                                             const float* __restrict__ bnsum, const float* __restrict__ bnsumsq,
                                             const float* __restrict__ gamma, const float* __restrict__ beta,
                                             float* __restrict__ out) {
    __shared__ float ssc[128], ssh[128];
    const int tid = threadIdx.x;
    if (tid < 128) {
        float mu = bnsum[tid] * (1.0f / NN);
        float var = bnsumsq[tid] * (1.0f / NN) - mu * mu;
        float rsv = rsqrtf(var + BN_EPS);
        float g = rsv * gamma[tid];
        ssc[tid] = g;
        ssh[tid] = beta[tid] - mu * g;
    }
    __syncthreads();

    const int wave = tid >> 6;
    const int lane = tid & 63;
    const int lr = lane & 15;
    const int lk = lane >> 4;
    const int r0 = (blockIdx.x * 4 + wave) * 16;

    bf16x8 a[4];
#pragma unroll
    for (int ks = 0; ks < 4; ++ks) {
        int kbase = ks * 32 + lk * 8;
        bf16x8 raw = *reinterpret_cast<const bf16x8*>(&h1b[(size_t)(r0 + lr) * 128 + kbase]);
        bf16x8 o;
#pragma unroll
        for (int j = 0; j < 8; ++j) {
            float v = __uint_as_float(((uint)(ushort)raw[j]) << 16);
            v = fmaxf(0.f, fmaf(v, ssc[kbase + j], ssh[kbase + j]));
            o[j] = (short)b1pack(v);
        }
        a[ks] = o;
    }

    f32x4 acc[8];
#pragma unroll
    for (int t = 0; t < 8; ++t) { acc[t][0] = 0.f; acc[t][1] = 0.f; acc[t][2] = 0.f; acc[t][3] = 0.f; }

#pragma unroll
    for (int t = 0; t < 8; ++t) {
        const ushort* wrow = &w2b[(size_t)(t * 16 + lr) * 128];
#pragma unroll
        for (int ks = 0; ks < 4; ++ks) {
            bf16x8 bfr = *reinterpret_cast<const bf16x8*>(&wrow[ks * 32 + lk * 8]);
            acc[t] = __builtin_amdgcn_mfma_f32_16x16x32_bf16(a[ks], bfr, acc[t], 0, 0, 0);
        }
    }
#pragma unroll
    for (int t = 0; t < 8; ++t) {
        float bias = b2[t * 16 + lr];
#pragma unroll
        for (int i = 0; i < 4; ++i)
            out[(size_t)(r0 + lk * 4 + i) * 128 + t * 16 + lr] = acc[t][i] + bias;
    }
}

extern "C" void kernel_launch(void* const* d_in, const int* in_sizes, int n_in,
                              void* d_out, int out_size, void* d_ws, size_t ws_size,
                              hipStream_t stream) {
    const float* x     = (const float*)d_in[0];
    const int*   ei    = (const int*)d_in[1];
    const float* W1    = (const float*)d_in[2];
    const float* b1    = (const float*)d_in[3];
    const float* gamma = (const float*)d_in[4];
    const float* beta  = (const float*)d_in[5];
    const float* W2    = (const float*)d_in[6];
    const float* b2    = (const float*)d_in[7];
    const float* eps   = (const float*)d_in[8];

    char* ws = (char*)d_ws;
    // ws layout (256B-aligned): cnt i32[40000] | srcl u16[40000*64] | xs bf16 slice-major[8][40000*16] |
    //   hb bf16[40000*128] | h1b bf16[40000*128] | w1b | w2b | bn f32[256]
    int*    cnt  = (int*)(ws + 0);
    ushort* srcl = (ushort*)(ws + 160000);
    uint*   xs   = (uint*)(ws + 5280000);
    uint*   hb   = (uint*)(ws + 15520000);
    ushort* h1b  = (ushort*)(ws + 25760000);
    uint*   w1b  = (uint*)(ws + 36000000);
    uint*   w2b  = (uint*)(ws + 36032768);
    float*  bn   = (float*)(ws + 36065536);
    float* bnsum   = bn;
    float* bnsumsq = bn + 128;

    hipMemsetAsync(cnt, 0, 160000, stream);
    k_prep<<<12517, 256, 0, stream>>>(x, W1, W2, ei, cnt, bn, xs, w1b, w2b, srcl);
    k_gather<<<10000, 256, 0, stream>>>(xs, cnt, srcl, eps, hb);
    k_mm1<<<625, 256, 0, stream>>>((const ushort*)hb, (const ushort*)w1b, b1, h1b, bnsum, bnsumsq);
    k_mm2<<<625, 256, 0, stream>>>(h1b, (const ushort*)w2b, b2, bnsum, bnsumsq, gamma, beta, (float*)d_out);
}

// Round 11
// 109.300 us; speedup vs baseline: 1.7589x; 1.7589x over previous
//
#include <hip/hip_runtime.h>

#define NN 40000
#define NE 640000
#define BN_EPS 1e-5f

typedef __attribute__((ext_vector_type(8))) short bf16x8;
typedef __attribute__((ext_vector_type(4))) float f32x4;
typedef unsigned int uint;
typedef unsigned short ushort;

__device__ __forceinline__ float blo(uint u) { return __uint_as_float(u << 16); }
__device__ __forceinline__ float bhi(uint u) { return __uint_as_float(u & 0xFFFF0000u); }
__device__ __forceinline__ uint bpack(float lo, float hi) {
    uint a = __float_as_uint(lo); a = (a + 0x7FFFu + ((a >> 16) & 1u)) >> 16;        // RNE
    uint b = __float_as_uint(hi); b = (b + 0x7FFFu + ((b >> 16) & 1u)) & 0xFFFF0000u;
    return a | b;
}
__device__ __forceinline__ ushort b1pack(float v) {
    uint u = __float_as_uint(v); return (ushort)((u + 0x7FFFu + ((u >> 16) & 1u)) >> 16);
}
__device__ __forceinline__ uint4 cvt8(const float4* f4, int i) {
    float4 p = f4[i * 2], q = f4[i * 2 + 1];
    uint4 o;
    o.x = bpack(p.x, p.y); o.y = bpack(p.z, p.w);
    o.z = bpack(q.x, q.y); o.w = bpack(q.z, q.w);
    return o;
}

// ---------------- K1: zero cnt+bn, x->bf16, W1->bf16, W2->bf16 (R5 known-best split) ----------------
__global__ __launch_bounds__(256) void k_pre(const float* __restrict__ x, const float* __restrict__ W1,
                                             const float* __restrict__ W2,
                                             int* __restrict__ cnt, float* __restrict__ bn,
                                             uint* __restrict__ xb, uint* __restrict__ w1b,
                                             uint* __restrict__ w2b) {
    int b = blockIdx.x, t = threadIdx.x;
    if (b < 157) {
        int i = b * 256 + t;
        if (i < NN) cnt[i] = 0;
        if (b == 156) bn[t] = 0.f;                     // bnsum[128]+bnsumsq[128]
    } else if (b < 2657) {
        int i = (b - 157) * 256 + t;                   // 640000 groups of 8 ch
        ((uint4*)xb)[i] = cvt8((const float4*)x, i);
    } else if (b < 2665) {
        int i = (b - 2657) * 256 + t;                  // 2048 groups (128x128)
        ((uint4*)w1b)[i] = cvt8((const float4*)W1, i);
    } else {
        int i = (b - 2665) * 256 + t;
        ((uint4*)w2b)[i] = cvt8((const float4*)W2, i);
    }
}

// ---------------- K2: bucket edges by dst (1 int atomic per edge), u16 src ids ----------------
__global__ __launch_bounds__(256) void k_bucket(const int* __restrict__ ei, int* __restrict__ cnt,
                                                ushort* __restrict__ srcl) {
    int e = blockIdx.x * 256 + threadIdx.x;
    if (e >= NE) return;
    int s = ei[e];
    int d = ei[NE + e];
    int pos = atomicAdd(&cnt[d], 1);
    if (pos < 64) srcl[d * 64 + pos] = (ushort)s;
}

// ---------------- K3: wave-per-node gather, SINGLE load batch (chain-length fix) ----------------
// Ten rounds showed gather time invariant to bytes/requests/miss-rate but always ~2.4 serial
// load round-trips per wave (dynamic chunk loop). Fix: issue 24 neighbor-row loads in ONE
// batch (deg<=24 covers ~98% of Poisson(16) nodes), sched_barrier(0) pins all loads before
// the accumulate (R3's compiler-reserialization fix), masked adds after a single waitcnt.
// Indices are readlane'd to SGPRs -> scalar saddr, ~24 data VGPRs live. Rare deg>24: serial tail.
__global__ __launch_bounds__(256) void k_gather(const uint* __restrict__ xbv, const int* __restrict__ cnt,
                                                const ushort* __restrict__ srcl, const float* __restrict__ epsp,
                                                uint* __restrict__ hb) {
    int wid = blockIdx.x * 4 + (threadIdx.x >> 6);    // one wave per node; grid*4 == NN
    int lane = threadIdx.x & 63;
    int deg = cnt[wid]; deg = deg > 64 ? 64 : deg;
    int sv = srcl[wid * 64 + lane];                   // neighbor ids in wave registers
    uint su = xbv[wid * 64 + lane];                   // self row (2 ch per lane)
    float e1 = 1.f + epsp[0];

    uint v[24];
#pragma unroll
    for (int j = 0; j < 24; ++j) {
        int s = __builtin_amdgcn_readlane(sv, j);     // SGPR id
        s = (j < deg) ? s : 0;                        // scalar cselect: clamp to row 0 (valid)
        v[j] = xbv[(size_t)s * 64 + lane];            // scalar base + lane offset
    }
    __builtin_amdgcn_sched_barrier(0);                // all 24 loads issued before any use

    float p0 = 0.f, p1 = 0.f, p2 = 0.f, p3 = 0.f;
    float r0 = 0.f, r1 = 0.f, r2 = 0.f, r3 = 0.f;
#pragma unroll
    for (int j = 0; j < 24; j += 4) {
        bool k0 = j + 0 < deg, k1 = j + 1 < deg, k2 = j + 2 < deg, k3 = j + 3 < deg;
        p0 += k0 ? blo(v[j + 0]) : 0.f;  r0 += k0 ? bhi(v[j + 0]) : 0.f;
        p1 += k1 ? blo(v[j + 1]) : 0.f;  r1 += k1 ? bhi(v[j + 1]) : 0.f;
        p2 += k2 ? blo(v[j + 2]) : 0.f;  r2 += k2 ? bhi(v[j + 2]) : 0.f;
        p3 += k3 ? blo(v[j + 3]) : 0.f;  r3 += k3 ? bhi(v[j + 3]) : 0.f;
    }
    float a0 = fmaf(blo(su), e1, (p0 + p1) + (p2 + p3));
    float a1 = fmaf(bhi(su), e1, (r0 + r1) + (r2 + r3));

    if (deg > 24) {                                   // rare (~2%) wave-uniform tail
        for (int base = 24; base < deg; base += 8) {
#pragma unroll
            for (int j = 0; j < 8; ++j) {
                int idx = base + j;
                int s = __builtin_amdgcn_readlane(sv, idx);
                bool ok = idx < deg;
                s = ok ? s : 0;
                uint vv = xbv[(size_t)s * 64 + lane];
                a0 += ok ? blo(vv) : 0.f;
                a1 += ok ? bhi(vv) : 0.f;
            }
        }
    }
    hb[wid * 64 + lane] = bpack(a0, a1);
}

// ---------------- K4: GEMM1 (MFMA bf16): h1b = bf16(hb @ W1b^T + b1), fused BN stats ----------------
// fragments: A[row=l&15][k=(l>>4)*8+j], B[k][col=l&15], C/D col=l&15,row=(l>>4)*4+i
__global__ __launch_bounds__(256) void k_mm1(const ushort* __restrict__ hb, const ushort* __restrict__ w1b,
                                             const float* __restrict__ b1, ushort* __restrict__ h1b,
                                             float* __restrict__ bnsum, float* __restrict__ bnsumsq) {
    __shared__ float rs[256 * 8];
    __shared__ float rq[256 * 8];
    const int tid = threadIdx.x;
    const int wave = tid >> 6;
    const int lane = tid & 63;
    const int lr = lane & 15;
    const int lk = lane >> 4;
    const int r0 = (blockIdx.x * 4 + wave) * 16;     // 625 blocks * 4 waves * 16 rows = 40000

    bf16x8 a[4];
#pragma unroll
    for (int ks = 0; ks < 4; ++ks)
        a[ks] = *reinterpret_cast<const bf16x8*>(&hb[(size_t)(r0 + lr) * 128 + ks * 32 + lk * 8]);

    f32x4 acc[8];
#pragma unroll
    for (int t = 0; t < 8; ++t) { acc[t][0] = 0.f; acc[t][1] = 0.f; acc[t][2] = 0.f; acc[t][3] = 0.f; }

#pragma unroll
    for (int t = 0; t < 8; ++t) {
        const ushort* wrow = &w1b[(size_t)(t * 16 + lr) * 128];
#pragma unroll
        for (int ks = 0; ks < 4; ++ks) {
            bf16x8 bfr = *reinterpret_cast<const bf16x8*>(&wrow[ks * 32 + lk * 8]);
            acc[t] = __builtin_amdgcn_mfma_f32_16x16x32_bf16(a[ks], bfr, acc[t], 0, 0, 0);
        }
    }
#pragma unroll
    for (int t = 0; t < 8; ++t) {
        float bias = b1[t * 16 + lr];
        float s = 0.f, q = 0.f;
#pragma unroll
        for (int i = 0; i < 4; ++i) {
            float v = acc[t][i] + bias;
            h1b[(size_t)(r0 + lk * 4 + i) * 128 + t * 16 + lr] = b1pack(v);
            s += v; q += v * v;
        }
        rs[tid * 8 + t] = s;
        rq[tid * 8 + t] = q;
    }
    __syncthreads();
    if (tid < 128) {
        int c = tid, t = c >> 4, cr = c & 15;
        float s = 0.f, q = 0.f;
#pragma unroll
        for (int w = 0; w < 4; ++w)
#pragma unroll
            for (int g = 0; g < 4; ++g) {
                int src = w * 64 + g * 16 + cr;
                s += rs[src * 8 + t];
                q += rq[src * 8 + t];
            }
        atomicAdd(&bnsum[c], s);
        atomicAdd(&bnsumsq[c], q);
    }
}

// ---------------- K5: GEMM2 (MFMA bf16): out = relu(bn(h1)) @ W2b^T + b2, BN inline ----------------
__global__ __launch_bounds__(256) void k_mm2(const ushort* __restrict__ h1b, const ushort* __restrict__ w2b,
                                             const float* __restrict__ b2,
                                             const float* __restrict__ bnsum, const float* __restrict__ bnsumsq,
                                             const float* __restrict__ gamma, const float* __restrict__ beta,
                                             float* __restrict__ out) {
    __shared__ float ssc[128], ssh[128];
    const int tid = threadIdx.x;
    if (tid < 128) {
        float mu = bnsum[tid] * (1.0f / NN);
        float var = bnsumsq[tid] * (1.0f / NN) - mu * mu;
        float rsv = rsqrtf(var + BN_EPS);
        float g = rsv * gamma[tid];
        ssc[tid] = g;
        ssh[tid] = beta[tid] - mu * g;
    }
    __syncthreads();

    const int wave = tid >> 6;
    const int lane = tid & 63;
    const int lr = lane & 15;
    const int lk = lane >> 4;
    const int r0 = (blockIdx.x * 4 + wave) * 16;

    bf16x8 a[4];
#pragma unroll
    for (int ks = 0; ks < 4; ++ks) {
        int kbase = ks * 32 + lk * 8;
        bf16x8 raw = *reinterpret_cast<const bf16x8*>(&h1b[(size_t)(r0 + lr) * 128 + kbase]);
        bf16x8 o;
#pragma unroll
        for (int j = 0; j < 8; ++j) {
            float v = __uint_as_float(((uint)(ushort)raw[j]) << 16);
            v = fmaxf(0.f, fmaf(v, ssc[kbase + j], ssh[kbase + j]));
            o[j] = (short)b1pack(v);
        }
        a[ks] = o;
    }

    f32x4 acc[8];
#pragma unroll
    for (int t = 0; t < 8; ++t) { acc[t][0] = 0.f; acc[t][1] = 0.f; acc[t][2] = 0.f; acc[t][3] = 0.f; }

#pragma unroll
    for (int t = 0; t < 8; ++t) {
        const ushort* wrow = &w2b[(size_t)(t * 16 + lr) * 128];
#pragma unroll
        for (int ks = 0; ks < 4; ++ks) {
            bf16x8 bfr = *reinterpret_cast<const bf16x8*>(&wrow[ks * 32 + lk * 8]);
            acc[t] = __builtin_amdgcn_mfma_f32_16x16x32_bf16(a[ks], bfr, acc[t], 0, 0, 0);
        }
    }
#pragma unroll
    for (int t = 0; t < 8; ++t) {
        float bias = b2[t * 16 + lr];
#pragma unroll
        for (int i = 0; i < 4; ++i)
            out[(size_t)(r0 + lk * 4 + i) * 128 + t * 16 + lr] = acc[t][i] + bias;
    }
}

extern "C" void kernel_launch(void* const* d_in, const int* in_sizes, int n_in,
                              void* d_out, int out_size, void* d_ws, size_t ws_size,
                              hipStream_t stream) {
    const float* x     = (const float*)d_in[0];
    const int*   ei    = (const int*)d_in[1];
    const float* W1    = (const float*)d_in[2];
    const float* b1    = (const float*)d_in[3];
    const float* gamma = (const float*)d_in[4];
    const float* beta  = (const float*)d_in[5];
    const float* W2    = (const float*)d_in[6];
    const float* b2    = (const float*)d_in[7];
    const float* eps   = (const float*)d_in[8];

    char* ws = (char*)d_ws;
    // ws layout (256B-aligned): cnt i32[40000] | srcl u16[40000*64] | xb bf16[40000*128] |
    //   hb bf16[40000*128] | h1b bf16[40000*128] | w1b | w2b | bn f32[256]
    int*    cnt  = (int*)(ws + 0);
    ushort* srcl = (ushort*)(ws + 160000);
    uint*   xb   = (uint*)(ws + 5280000);
    uint*   hb   = (uint*)(ws + 15520000);
    ushort* h1b  = (ushort*)(ws + 25760000);
    uint*   w1b  = (uint*)(ws + 36000000);
    uint*   w2b  = (uint*)(ws + 36032768);
    float*  bn   = (float*)(ws + 36065536);
    float* bnsum   = bn;
    float* bnsumsq = bn + 128;

    k_pre<<<2673, 256, 0, stream>>>(x, W1, W2, cnt, bn, xb, w1b, w2b);
    k_bucket<<<2500, 256, 0, stream>>>(ei, cnt, srcl);
    k_gather<<<10000, 256, 0, stream>>>(xb, cnt, srcl, eps, hb);
    k_mm1<<<625, 256, 0, stream>>>((const ushort*)hb, (const ushort*)w1b, b1, h1b, bnsum, bnsumsq);
    k_mm2<<<625, 256, 0, stream>>>(h1b, (const ushort*)w2b, b2, bnsum, bnsumsq, gamma, beta, (float*)d_out);
}